// Round 7
// baseline (19.414 us; speedup 1.0000x reference)
//
#include <hip/hip_runtime.h>
#include <hip/hip_bf16.h>

// Masked one-hot, ONE pass, no barrier (R5 structure), with NON-TEMPORAL
// stores. R6 fix: __builtin_nontemporal_store needs a NATIVE vector type,
// not HIP's struct float4 — use ext_vector_type(4) float.
//   - each block owns 16 KB (4096 floats) covering <=8 rows
//   - block-uniform SGPR hot-table: H4[i] = (r*607+lab)>>2, nibble P[i]
//   - per thread: 4 x 16B NT stores in the rocclr-fill pattern
//     (lane-contiguous 4 KB stride); data from compare chain vs sentinels
// R2: inter-lane contiguity per store is mandatory. R3: +1 dispatch = +7us.
// R4: vmcnt(0) barrier tail small. R5: VALU/order variants all ~17us.

#define BB 256
#define NN 128
#define CC 607
#define NROWS (BB * NN)               // 32768
#define TOTAL (NROWS * CC)            // 19,890,176 floats
#define NV4   (TOTAL / 4)             // 4,972,544 float4
#define NBLOCKS (NV4 / 1024)          // 4856; block owns 4096 floats (16 KB)

typedef float f32x4 __attribute__((ext_vector_type(4)));  // native vector for nt builtin

__global__ __launch_bounds__(256) void onehot_nt_kernel(const int* __restrict__ labels,
                                                        float* __restrict__ out) {
    const int b = blockIdx.x;
    const int tid = threadIdx.x;
    const int lo = b * 4096;                       // first owned float
    const unsigned rlo = (unsigned)lo / (unsigned)CC;  // one division, uniform

    // Block-uniform hot-element table (SGPR-resident; static indexing only).
    unsigned H4[8];
    int P[8];
#pragma unroll
    for (int i = 0; i < 8; ++i) {
        unsigned r = rlo + i;
        unsigned rc = (r < NROWS) ? r : (NROWS - 1);   // clamp read
        int lab = labels[rc];                          // uniform scalar load, L2-hot
        int h = (int)(r * CC) + lab;
        bool valid = (r < NROWS) & (lab >= 0) & (h >= lo) & (h < lo + 4096);
        H4[i] = valid ? (unsigned)(h >> 2) : 0xFFFFFFFFu;  // sentinel: no match
        P[i] = 1 << (h & 3);
    }

    const unsigned F0 = (unsigned)b * 1024u + (unsigned)tid;  // first float4 index
    f32x4* o4 = reinterpret_cast<f32x4*>(out) + F0;

#pragma unroll
    for (int j = 0; j < 4; ++j) {
        const unsigned F = F0 + 256u * j;
        int pat = 0;
#pragma unroll
        for (int i = 0; i < 8; ++i)
            pat |= (F == H4[i]) ? P[i] : 0;        // v_cmp + cndmask + or
        f32x4 v;
        v.x = (pat & 1) ? 1.0f : 0.0f;
        v.y = (pat & 2) ? 1.0f : 0.0f;
        v.z = (pat & 4) ? 1.0f : 0.0f;
        v.w = (pat & 8) ? 1.0f : 0.0f;
        __builtin_nontemporal_store(v, &o4[j * 256]);  // nt: bypass L2 retention
    }
}

extern "C" void kernel_launch(void* const* d_in, const int* in_sizes, int n_in,
                              void* d_out, int out_size, void* d_ws, size_t ws_size,
                              hipStream_t stream) {
    // d_in[0] = obj_sem_cls_pred (unused), d_in[1] = obj_labels (int32 on device),
    // d_in[2] = cur_step, d_in[3] = total_steps (unused).
    const int* labels = (const int*)d_in[1];
    float* out = (float*)d_out;

    onehot_nt_kernel<<<NBLOCKS, 256, 0, stream>>>(labels, out);
}

// Round 8
// 18.792 us; speedup vs baseline: 1.0331x; 1.0331x over previous
//
#include <hip/hip_runtime.h>
#include <hip/hip_bf16.h>

// Masked one-hot, ONE pass, no barrier, PERSISTENT GRID.
// R7 lesson: NT stores regress (+2.2us) — L2 write-combining helps streams.
// Model: time ~= bytes/7.6TB/s + ~5us fixed (graph node + ramp). This round
// attacks the fixed part: 1214 blocks (<=4.7/CU, fully resident, zero block
// churn), each handling 4 consecutive 16KB regions with the R5 merged-store
// pattern (store data carries the 1.0f; no barrier, no second phase).
//   per region: block-uniform SGPR hot-table (8 rows), per thread 4x16B
//   stores, lane-contiguous at 4KB stride (rocclr-fill pattern).
// R2: inter-lane contiguity per store is mandatory. R3: +1 dispatch ~ +2us.

#define BB 256
#define NN 128
#define CC 607
#define NROWS (BB * NN)               // 32768
#define TOTAL (NROWS * CC)            // 19,890,176 floats
#define NV4   (TOTAL / 4)             // 4,972,544 float4
#define NREGIONS (NV4 / 1024)         // 4856 regions of 4096 floats (16 KB)
#define REG_PER_BLOCK 4
#define NBLOCKS (NREGIONS / REG_PER_BLOCK)   // 1214, exact

__global__ __launch_bounds__(256) void onehot_persist_kernel(const int* __restrict__ labels,
                                                             float* __restrict__ out) {
    const int tid = threadIdx.x;

#pragma unroll
    for (int k = 0; k < REG_PER_BLOCK; ++k) {
        const int reg = blockIdx.x * REG_PER_BLOCK + k;   // owned region id
        const int lo = reg * 4096;                        // first owned float
        const unsigned rlo = (unsigned)lo / (unsigned)CC; // one division, uniform

        // Block-uniform hot-element table (SGPR; static indexing only).
        unsigned H4[8];
        int P[8];
#pragma unroll
        for (int i = 0; i < 8; ++i) {
            unsigned r = rlo + i;
            unsigned rc = (r < NROWS) ? r : (NROWS - 1);  // clamp read
            int lab = labels[rc];                         // uniform scalar load
            int h = (int)(r * CC) + lab;
            bool valid = (r < NROWS) & (lab >= 0) & (h >= lo) & (h < lo + 4096);
            H4[i] = valid ? (unsigned)(h >> 2) : 0xFFFFFFFFu;
            P[i] = 1 << (h & 3);
        }

        const unsigned F0 = (unsigned)reg * 1024u + (unsigned)tid;
        float4* o4 = reinterpret_cast<float4*>(out) + F0;

#pragma unroll
        for (int j = 0; j < 4; ++j) {
            const unsigned F = F0 + 256u * j;
            int pat = 0;
#pragma unroll
            for (int i = 0; i < 8; ++i)
                pat |= (F == H4[i]) ? P[i] : 0;           // v_cmp + cndmask + or
            float4 v;
            v.x = (pat & 1) ? 1.0f : 0.0f;
            v.y = (pat & 2) ? 1.0f : 0.0f;
            v.z = (pat & 4) ? 1.0f : 0.0f;
            v.w = (pat & 8) ? 1.0f : 0.0f;
            o4[j * 256] = v;                              // memset-identical pattern
        }
    }
}

extern "C" void kernel_launch(void* const* d_in, const int* in_sizes, int n_in,
                              void* d_out, int out_size, void* d_ws, size_t ws_size,
                              hipStream_t stream) {
    // d_in[0] = obj_sem_cls_pred (unused), d_in[1] = obj_labels (int32 on device),
    // d_in[2] = cur_step, d_in[3] = total_steps (unused).
    const int* labels = (const int*)d_in[1];
    float* out = (float*)d_out;

    onehot_persist_kernel<<<NBLOCKS, 256, 0, stream>>>(labels, out);
}

// Round 9
// 16.948 us; speedup vs baseline: 1.1455x; 1.1088x over previous
//
#include <hip/hip_runtime.h>
#include <hip/hip_bf16.h>

// Masked one-hot — BEST variant (R4): single fused kernel, block-region
// ownership. Reverted here after R5/R7/R8 A/Bs all regressed or tied:
//   R5 merged-store (no barrier)      17.2us   (tie/noise)
//   R7 non-temporal stores            19.4us   (L2 write-combining matters)
//   R8 persistent 1214-block grid     18.8us   (per-block serialization)
// Ladder floor model (validated on harness 318MB fills = 42us data + ~4-5us
// fixed): 79.6MB writes -> ~10.5-11.4us data + ~4-5us graph/ramp overhead
// ~= 15.5-16.5us. R4's 16.9us is within a few % -> write-roofline.
//
//   phase 1: each block zero-fills its exclusive 16 KB region using the
//            rocclr fillBuffer store pattern (4x float4/thread, 4 KB
//            stride -> every store inter-lane contiguous, ~7 TB/s).
//   __syncthreads() (vmcnt(0) drain + barrier: region zeros visible).
//   phase 2: threads 0..7 probe the <=8 rows overlapping this region and
//            write 1.0f at row*607+label IFF it lies inside the region.

#define BB 256
#define NN 128
#define CC 607
#define NROWS (BB * NN)               // 32768
#define TOTAL (NROWS * CC)            // 19,890,176 floats
#define NV4   (TOTAL / 4)             // 4,972,544 = 4856 * 1024 exactly
#define NBLOCKS (NV4 / 1024)          // 4856; each block owns 4096 floats (16 KB)

__global__ __launch_bounds__(256) void onehot_fused_kernel(const int* __restrict__ labels,
                                                           float* __restrict__ out) {
    const int b = blockIdx.x;
    const int tid = threadIdx.x;

    // ---- phase 1: zero-fill own region (memset-identical pattern) ----
    float4* o4 = reinterpret_cast<float4*>(out) + b * 1024 + tid;
    const float4 z = make_float4(0.f, 0.f, 0.f, 0.f);
    o4[0]   = z;
    o4[256] = z;
    o4[512] = z;
    o4[768] = z;

    __syncthreads();  // vmcnt(0) drain + barrier: region zeros are visible

    // ---- phase 2: set hot elements inside own region ----
    if (tid < 8) {
        const int lo = b * 4096;              // first float owned
        const int hi = lo + 4096;             // one past last
        unsigned rlo = (unsigned)lo / (unsigned)CC;   // magic-mul division
        unsigned r = rlo + tid;
        if (r < NROWS && (int)(r * CC) < hi) {        // row starts before region end
            int lab = labels[r];
            if (lab >= 0) {
                int flat = (int)(r * CC) + lab;
                if (flat >= lo && flat < hi)          // exclusive ownership
                    out[flat] = 1.0f;
            }
        }
    }
}

extern "C" void kernel_launch(void* const* d_in, const int* in_sizes, int n_in,
                              void* d_out, int out_size, void* d_ws, size_t ws_size,
                              hipStream_t stream) {
    // d_in[0] = obj_sem_cls_pred (unused), d_in[1] = obj_labels (int32 on device),
    // d_in[2] = cur_step, d_in[3] = total_steps (unused).
    const int* labels = (const int*)d_in[1];
    float* out = (float*)d_out;

    onehot_fused_kernel<<<NBLOCKS, 256, 0, stream>>>(labels, out);
}